// Round 1
// baseline (194.230 us; speedup 1.0000x reference)
//
#include <hip/hip_runtime.h>
#include <math.h>

#define I1c 4
#define I2c 30
#define I3c 30
#define Rc  5
#define Oc  2
#define NWc (I1c * I2c * I3c)   /* 3600 */
#define NV  (NWc / 4)           /* 900 float4 per row */

// ---------------------------------------------------------------------------
// Kernel 1: fold a,b,c,d into W[2][3600] (two float planes, o-major) in d_ws.
// W[n][o] = sum_{r,s,t} a[i,r] b[r,j,s] c[s,o,t] d[t,k],  n=(i*30+j)*30+k
// ---------------------------------------------------------------------------
__global__ __launch_bounds__(256) void tn_prep(const float* __restrict__ A,
                                               const float* __restrict__ B,
                                               const float* __restrict__ C,
                                               const float* __restrict__ D,
                                               float* __restrict__ W) {
    int n = blockIdx.x * 256 + threadIdx.x;
    if (n >= NWc) return;
    int i = n / (I2c * I3c);
    int j = (n / I3c) % I2c;
    int k = n % I3c;
    float acc0 = 0.f, acc1 = 0.f;
    for (int r = 0; r < Rc; ++r) {
        float ar = A[i * Rc + r];
        for (int s = 0; s < Rc; ++s) {
            float f = ar * B[(r * I2c + j) * Rc + s];
            float g0 = 0.f, g1 = 0.f;
            for (int t = 0; t < Rc; ++t) {
                float dt = D[t * I3c + k];
                g0 = fmaf(C[(s * Oc + 0) * Rc + t], dt, g0);
                g1 = fmaf(C[(s * Oc + 1) * Rc + t], dt, g1);
            }
            acc0 = fmaf(f, g0, acc0);
            acc1 = fmaf(f, g1, acc1);
        }
    }
    W[n]       = acc0;
    W[NWc + n] = acc1;
}

// ---------------------------------------------------------------------------
// Kernel 2: out[row] = swish(x[row,:] . W[:,o] + bias[o])
// One wave per row; float4-coalesced row reads; W staged in LDS planes.
// ---------------------------------------------------------------------------
__global__ __launch_bounds__(256) void tn_main(const float* __restrict__ x,
                                               const float* __restrict__ W,
                                               const float* __restrict__ bias,
                                               float2* __restrict__ out,
                                               int nrows) {
    __shared__ __align__(16) float lw0[NWc];
    __shared__ __align__(16) float lw1[NWc];
    for (int t = threadIdx.x; t < NWc; t += 256) {
        lw0[t] = W[t];
        lw1[t] = W[NWc + t];
    }
    __syncthreads();

    const float b0 = bias[0], b1 = bias[1];
    const int wave = threadIdx.x >> 6;
    const int lane = threadIdx.x & 63;
    const int rowStride = gridDim.x * 4;

    for (int row = blockIdx.x * 4 + wave; row < nrows; row += rowStride) {
        const float4* __restrict__ xr =
            reinterpret_cast<const float4*>(x + (size_t)row * NWc);
        float acc0 = 0.f, acc1 = 0.f;

        // 900 float4 per row = 14 full wave-iterations + 4-lane tail
        #pragma unroll
        for (int it = 0; it < 14; ++it) {
            const int v = lane + 64 * it;
            const float4 xv = xr[v];
            const float4 w0 = *reinterpret_cast<const float4*>(&lw0[4 * v]);
            const float4 w1 = *reinterpret_cast<const float4*>(&lw1[4 * v]);
            acc0 += xv.x * w0.x + xv.y * w0.y + xv.z * w0.z + xv.w * w0.w;
            acc1 += xv.x * w1.x + xv.y * w1.y + xv.z * w1.z + xv.w * w1.w;
        }
        if (lane < 4) {
            const int v = 896 + lane;
            const float4 xv = xr[v];
            const float4 w0 = *reinterpret_cast<const float4*>(&lw0[4 * v]);
            const float4 w1 = *reinterpret_cast<const float4*>(&lw1[4 * v]);
            acc0 += xv.x * w0.x + xv.y * w0.y + xv.z * w0.z + xv.w * w0.w;
            acc1 += xv.x * w1.x + xv.y * w1.y + xv.z * w1.z + xv.w * w1.w;
        }

        // 64-lane butterfly reduce
        #pragma unroll
        for (int off = 32; off > 0; off >>= 1) {
            acc0 += __shfl_down(acc0, off, 64);
            acc1 += __shfl_down(acc1, off, 64);
        }

        if (lane == 0) {
            const float v0 = acc0 + b0;
            const float v1 = acc1 + b1;
            out[row] = make_float2(v0 / (1.f + expf(-v0)),
                                   v1 / (1.f + expf(-v1)));
        }
    }
}

extern "C" void kernel_launch(void* const* d_in, const int* in_sizes, int n_in,
                              void* d_out, int out_size, void* d_ws, size_t ws_size,
                              hipStream_t stream) {
    const float* x    = (const float*)d_in[0];
    const float* a    = (const float*)d_in[1];
    const float* b    = (const float*)d_in[2];
    const float* c    = (const float*)d_in[3];
    const float* d    = (const float*)d_in[4];
    const float* bias = (const float*)d_in[5];
    float* W = (float*)d_ws;                 // 2 * 3600 floats = 28.8 KB
    float2* out = (float2*)d_out;

    const int nrows = in_sizes[0] / NWc;     // 65536

    tn_prep<<<(NWc + 255) / 256, 256, 0, stream>>>(a, b, c, d, W);

    const int grid = 2048;                   // 4 rows/block-iter, 8 sweeps
    tn_main<<<grid, 256, 0, stream>>>(x, W, bias, out, nrows);
}

// Round 2
// 148.327 us; speedup vs baseline: 1.3095x; 1.3095x over previous
//
#include <hip/hip_runtime.h>
#include <math.h>

#define I1c 4
#define I2c 30
#define I3c 30
#define Rc  5
#define Oc  2
#define NWc (I1c * I2c * I3c)   /* 3600 */

typedef float f32x4 __attribute__((ext_vector_type(4)));

// ---------------------------------------------------------------------------
// Kernel 1: fold a,b,c,d into W[2][3600] (two float planes, o-major) in d_ws.
// ---------------------------------------------------------------------------
__global__ __launch_bounds__(256) void tn_prep(const float* __restrict__ A,
                                               const float* __restrict__ B,
                                               const float* __restrict__ C,
                                               const float* __restrict__ D,
                                               float* __restrict__ W) {
    int n = blockIdx.x * 256 + threadIdx.x;
    if (n >= NWc) return;
    int i = n / (I2c * I3c);
    int j = (n / I3c) % I2c;
    int k = n % I3c;
    float acc0 = 0.f, acc1 = 0.f;
    for (int r = 0; r < Rc; ++r) {
        float ar = A[i * Rc + r];
        for (int s = 0; s < Rc; ++s) {
            float f = ar * B[(r * I2c + j) * Rc + s];
            float g0 = 0.f, g1 = 0.f;
            for (int t = 0; t < Rc; ++t) {
                float dt = D[t * I3c + k];
                g0 = fmaf(C[(s * Oc + 0) * Rc + t], dt, g0);
                g1 = fmaf(C[(s * Oc + 1) * Rc + t], dt, g1);
            }
            acc0 = fmaf(f, g0, acc0);
            acc1 = fmaf(f, g1, acc1);
        }
    }
    W[n]       = acc0;
    W[NWc + n] = acc1;
}

// ---------------------------------------------------------------------------
// Kernel 2: out[row] = swish(x[row,:] . W[:,o] + bias[o])
// One wave per row-slot. W held ENTIRELY in registers (row-invariant per
// lane). x read with non-temporal float4 loads (read-once stream, skip
// cache allocation). No LDS in the hot loop.
// ---------------------------------------------------------------------------
__global__ __launch_bounds__(256) void tn_main(const float* __restrict__ x,
                                               const float* __restrict__ W,
                                               const float* __restrict__ bias,
                                               float2* __restrict__ out,
                                               int nrows) {
    const int wave = threadIdx.x >> 6;
    const int lane = threadIdx.x & 63;

    const f32x4* __restrict__ W0 = reinterpret_cast<const f32x4*>(W);
    const f32x4* __restrict__ W1 = reinterpret_cast<const f32x4*>(W + NWc);

    // Hoist W into registers: lane's elements are invariant across rows.
    f32x4 w0[14], w1[14];
    #pragma unroll
    for (int it = 0; it < 14; ++it) {
        w0[it] = W0[lane + 64 * it];
        w1[it] = W1[lane + 64 * it];
    }
    // Tail (900 = 14*64 + 4): lanes >= 4 hold zeros -> branch-free FMA.
    f32x4 w0t = {0.f, 0.f, 0.f, 0.f};
    f32x4 w1t = {0.f, 0.f, 0.f, 0.f};
    if (lane < 4) {
        w0t = W0[896 + lane];
        w1t = W1[896 + lane];
    }

    const float b0 = bias[0], b1 = bias[1];
    const int rowStride = gridDim.x * 4;

    for (int row = blockIdx.x * 4 + wave; row < nrows; row += rowStride) {
        const f32x4* __restrict__ xr =
            reinterpret_cast<const f32x4*>(x + (size_t)row * NWc);

        // Issue all 15 row loads up front (max memory-level parallelism).
        f32x4 xv[14];
        #pragma unroll
        for (int it = 0; it < 14; ++it)
            xv[it] = __builtin_nontemporal_load(&xr[lane + 64 * it]);
        f32x4 xt = {0.f, 0.f, 0.f, 0.f};
        if (lane < 4)
            xt = __builtin_nontemporal_load(&xr[896 + lane]);

        float acc0 = 0.f, acc1 = 0.f;
        #pragma unroll
        for (int it = 0; it < 14; ++it) {
            acc0 += xv[it][0] * w0[it][0] + xv[it][1] * w0[it][1]
                  + xv[it][2] * w0[it][2] + xv[it][3] * w0[it][3];
            acc1 += xv[it][0] * w1[it][0] + xv[it][1] * w1[it][1]
                  + xv[it][2] * w1[it][2] + xv[it][3] * w1[it][3];
        }
        acc0 += xt[0] * w0t[0] + xt[1] * w0t[1] + xt[2] * w0t[2] + xt[3] * w0t[3];
        acc1 += xt[0] * w1t[0] + xt[1] * w1t[1] + xt[2] * w1t[2] + xt[3] * w1t[3];

        // 64-lane butterfly reduce.
        #pragma unroll
        for (int off = 32; off > 0; off >>= 1) {
            acc0 += __shfl_down(acc0, off, 64);
            acc1 += __shfl_down(acc1, off, 64);
        }

        if (lane == 0) {
            const float v0 = acc0 + b0;
            const float v1 = acc1 + b1;
            out[row] = make_float2(v0 / (1.f + expf(-v0)),
                                   v1 / (1.f + expf(-v1)));
        }
    }
}

extern "C" void kernel_launch(void* const* d_in, const int* in_sizes, int n_in,
                              void* d_out, int out_size, void* d_ws, size_t ws_size,
                              hipStream_t stream) {
    const float* x    = (const float*)d_in[0];
    const float* a    = (const float*)d_in[1];
    const float* b    = (const float*)d_in[2];
    const float* c    = (const float*)d_in[3];
    const float* d    = (const float*)d_in[4];
    const float* bias = (const float*)d_in[5];
    float* W = (float*)d_ws;                 // 2 * 3600 floats = 28.8 KB
    float2* out = (float2*)d_out;

    const int nrows = in_sizes[0] / NWc;     // 65536

    tn_prep<<<(NWc + 255) / 256, 256, 0, stream>>>(a, b, c, d, W);

    const int grid = 2048;                   // 4 rows/block-iter, 8 sweeps
    tn_main<<<grid, 256, 0, stream>>>(x, W, bias, out, nrows);
}